// Round 2
// 1418.306 us; speedup vs baseline: 1.2331x; 1.2331x over previous
//
#include <hip/hip_runtime.h>
#include <hip/hip_bf16.h>

typedef __attribute__((ext_vector_type(4))) int i32x4;

// ---------------------------------------------------------------------------
// exact pow2 ceil: smallest power of two >= s  (s > 0, normal)
// ---------------------------------------------------------------------------
__device__ inline float pow2_ceil(float s) {
    unsigned u = __float_as_uint(s);
    if ((u & 0x007fffffu) == 0) return s;              // exact power of two
    return __uint_as_float(((u >> 23) + 1) << 23);     // bump exponent
}

// ---------------------------------------------------------------------------
// column absmax (unchanged this round)
// ---------------------------------------------------------------------------
__global__ __launch_bounds__(256) void colmax_kernel(
    const float* __restrict__ src, int K, float* __restrict__ out)
{
    int col = (blockIdx.x * 256 + threadIdx.x) * 4;
    const float* p = src + (size_t)blockIdx.y * 64 * K + col;
    float mx = 0.f, my = 0.f, mz = 0.f, mw = 0.f;
    for (int r = 0; r < 64; ++r) {
        float4 v = *(const float4*)p;
        mx = fmaxf(mx, fabsf(v.x));
        my = fmaxf(my, fabsf(v.y));
        mz = fmaxf(mz, fabsf(v.z));
        mw = fmaxf(mw, fabsf(v.w));
        p += K;
    }
    atomicMax((unsigned int*)(out + col + 0), __float_as_uint(mx));
    atomicMax((unsigned int*)(out + col + 1), __float_as_uint(my));
    atomicMax((unsigned int*)(out + col + 2), __float_as_uint(mz));
    atomicMax((unsigned int*)(out + col + 3), __float_as_uint(mw));
}

__global__ __launch_bounds__(256) void smooth_kernel(
    const float* __restrict__ xmax, const float* __restrict__ wmax,
    float* __restrict__ smooth, int K)
{
    int i = blockIdx.x * 256 + threadIdx.x;
    if (i < K) smooth[i] = sqrtf(xmax[i] * wmax[i]);
}

// ---------------------------------------------------------------------------
// per-row quant (unchanged this round — math must stay bit-identical)
// ---------------------------------------------------------------------------
template <bool MUL>
__global__ __launch_bounds__(256) void quant_kernel(
    const float* __restrict__ src, const float* __restrict__ smooth,
    signed char* __restrict__ q, float* __restrict__ scale_out, int K)
{
    __shared__ float red[4];
    const int row = blockIdx.x;
    const int tid = threadIdx.x;
    const float* sr = src + (size_t)row * K;

    float v[16];
    float amax = 0.f;
#pragma unroll
    for (int c = 0; c < 4; ++c) {
        int idx = (c << 10) + (tid << 2);
        float4 xv = *(const float4*)(sr + idx);
        float4 sv = *(const float4*)(smooth + idx);
        float a, b, cc, d;
        if (MUL) { a = xv.x * sv.x; b = xv.y * sv.y; cc = xv.z * sv.z; d = xv.w * sv.w; }
        else     { a = xv.x / sv.x; b = xv.y / sv.y; cc = xv.z / sv.z; d = xv.w / sv.w; }
        v[c*4+0] = a; v[c*4+1] = b; v[c*4+2] = cc; v[c*4+3] = d;
        amax = fmaxf(amax, fmaxf(fmaxf(fabsf(a), fabsf(b)), fmaxf(fabsf(cc), fabsf(d))));
    }
#pragma unroll
    for (int off = 32; off > 0; off >>= 1)
        amax = fmaxf(amax, __shfl_down(amax, off, 64));
    if ((tid & 63) == 0) red[tid >> 6] = amax;
    __syncthreads();
    float m = fmaxf(fmaxf(red[0], red[1]), fmaxf(red[2], red[3]));

    float s = fmaxf(m / 127.0f, 1e-30f);
    float scale = pow2_ceil(s);
    if (tid == 0) scale_out[row] = scale;
    float inv = 1.0f / scale;

#pragma unroll
    for (int c = 0; c < 4; ++c) {
        char4 o;
        o.x = (signed char)(int)fminf(fmaxf(rintf(v[c*4+0] * inv), -127.f), 127.f);
        o.y = (signed char)(int)fminf(fmaxf(rintf(v[c*4+1] * inv), -127.f), 127.f);
        o.z = (signed char)(int)fminf(fmaxf(rintf(v[c*4+2] * inv), -127.f), 127.f);
        o.w = (signed char)(int)fminf(fmaxf(rintf(v[c*4+3] * inv), -127.f), 127.f);
        *(char4*)(q + (size_t)row * K + (c << 10) + (tid << 2)) = o;
    }
}

// ---------------------------------------------------------------------------
// i8 GEMM, 256x256 8-phase template (T1+T2+T3+T4+T5 per learn_hip m201):
//   BM=BN=256, BK=128 i8 (128B rows = same byte geometry as bf16 BK=64)
//   8 waves (2M x 4N), 512 thr; per-wave output 128x64
//   LDS 128 KiB: 2 dbuf x 2 K-slabs(64B) x (A 16KB + B 16KB)
//   per K-tile: 4 phases x 16 mfma_i32_16x16x64_i8; counted vmcnt(4) 2x/tile
//   XOR swizzle: phys 16B-slot = logical ^ (row & 3), applied on global src
//   (LDS dest linear — global_load_lds constraint) and on ds_read address.
// vmcnt ledger (per wave): prologue 8 -> vmcnt(4) [ks0 landed];
//   P1 +2, P2 +2 -> vmcnt(4) retires ks1(t); P3 +2, P4 +2 -> vmcnt(4)
//   retires ks0(t+1). Closed, uniform, never drains to 0 in the loop.
// ---------------------------------------------------------------------------
#define G2L(g, l) __builtin_amdgcn_global_load_lds( \
    (const __attribute__((address_space(1))) unsigned char*)(g), \
    (__attribute__((address_space(3))) unsigned char*)(l), 16, 0, 0)

__global__ __launch_bounds__(512, 2) void gemm_i8_256(
    const signed char* __restrict__ Aq, const signed char* __restrict__ Bq,
    const float* __restrict__ xs, const float* __restrict__ wsc,
    const float* __restrict__ bias, float* __restrict__ out,
    int M, int N, int K)
{
    __shared__ signed char lds[131072];   // A: [0,64K) B: [64K,128K)

    const int tid = threadIdx.x;

    // T1: bijective XCD-aware block swizzle (m204 formula)
    const int nbx = gridDim.x;                       // N/256
    int lid = blockIdx.y * nbx + blockIdx.x;
    const int nwg = nbx * gridDim.y;
    const int q8 = nwg >> 3, r8 = nwg & 7;
    const int xcd = lid & 7, idx = lid >> 3;
    lid = (xcd < r8 ? xcd * (q8 + 1) : r8 * (q8 + 1) + (xcd - r8) * q8) + idx;
    const int bm = lid / nbx, bn = lid % nbx;

    const int lane = tid & 63;
    const int wave = tid >> 6;
    const int r16 = lane & 15, quad = lane >> 4;
    const int wr = wave >> 2;        // 0..1  (M half: 128 rows)
    const int wc = wave & 3;         // 0..3  (N quarter: 64 cols)

    const signed char* Ab = Aq + (size_t)(bm * 256) * K;
    const signed char* Bb = Bq + (size_t)(bn * 256) * K;

    // staging geometry: pass p covers slab rows p*128 + (tid>>2), slot tid&3
    const int srow  = tid >> 2;
    const int sslot = tid & 3;
    const int gslot = ((sslot ^ (srow & 3)) << 4);   // swizzled 16B slot in 64B slab row
    const size_t arow0 = (size_t)srow * K;
    const size_t arow1 = (size_t)(srow + 128) * K;
    const int sdst = tid << 4;                       // linear LDS dest (+ p*8192)

    // reader lane offsets: phys slot = quad ^ (row & 3); row&3 == r16&3
    const int sw   = (quad ^ (r16 & 3)) << 4;
    const int aoff = ((wr * 128 + r16) << 6) + sw;           // + mi*1024 + ks*16384 + buf
    const int boff = 65536 + ((wc * 64 + r16) << 6) + sw;    // + ni*1024 + ks*16384 + buf

    i32x4 acc[8][4] = {};
    const int NT = K >> 7;   // K-tiles of 128

    // ---- prologue: stage all 4 slabs of tile 0 into buf 0 ----
    G2L(Ab + arow0 + gslot,              lds + sdst);                      // A-ks0
    G2L(Ab + arow1 + gslot,              lds + 8192 + sdst);
    G2L(Bb + arow0 + gslot,              lds + 65536 + sdst);              // B-ks0
    G2L(Bb + arow1 + gslot,              lds + 65536 + 8192 + sdst);
    G2L(Ab + arow0 + 64 + gslot,         lds + 16384 + sdst);              // A-ks1
    G2L(Ab + arow1 + 64 + gslot,         lds + 16384 + 8192 + sdst);
    G2L(Bb + arow0 + 64 + gslot,         lds + 65536 + 16384 + sdst);      // B-ks1
    G2L(Bb + arow1 + 64 + gslot,         lds + 65536 + 16384 + 8192 + sdst);
    asm volatile("s_waitcnt vmcnt(4)" ::: "memory");   // ks0 slabs landed
    __builtin_amdgcn_s_barrier();

    for (int t = 0; t < NT; ++t) {
        const int bofs  = (t & 1) << 15;
        const int nbofs = bofs ^ 32768;
        const size_t kc = (size_t)((t + 1 < NT) ? (t + 1) : t) << 7;  // clamped prefetch
        i32x4 af[4], bf[4];

        // ---- P1: ks0, mh0 | stage A-ks0(t+1) ----
#pragma unroll
        for (int mi = 0; mi < 4; ++mi)
            af[mi] = *(const i32x4*)(lds + bofs + aoff + mi * 1024);
#pragma unroll
        for (int ni = 0; ni < 4; ++ni)
            bf[ni] = *(const i32x4*)(lds + bofs + boff + ni * 1024);
        G2L(Ab + arow0 + kc + gslot, lds + nbofs + sdst);
        G2L(Ab + arow1 + kc + gslot, lds + nbofs + 8192 + sdst);
        __builtin_amdgcn_s_barrier();
        __builtin_amdgcn_s_setprio(1);
#pragma unroll
        for (int mi = 0; mi < 4; ++mi)
#pragma unroll
            for (int ni = 0; ni < 4; ++ni)
                acc[mi][ni] = __builtin_amdgcn_mfma_i32_16x16x64_i8(af[mi], bf[ni], acc[mi][ni], 0, 0, 0);
        __builtin_amdgcn_s_setprio(0);
        __builtin_amdgcn_s_barrier();

        // ---- P2: ks0, mh1 | stage B-ks0(t+1) | vmcnt(4) ----
#pragma unroll
        for (int mi = 0; mi < 4; ++mi)
            af[mi] = *(const i32x4*)(lds + bofs + aoff + 4096 + mi * 1024);
        G2L(Bb + arow0 + kc + gslot, lds + nbofs + 65536 + sdst);
        G2L(Bb + arow1 + kc + gslot, lds + nbofs + 65536 + 8192 + sdst);
        asm volatile("s_waitcnt vmcnt(4)" ::: "memory");   // ks1(t) slabs landed
        __builtin_amdgcn_s_barrier();
        __builtin_amdgcn_s_setprio(1);
#pragma unroll
        for (int mi = 0; mi < 4; ++mi)
#pragma unroll
            for (int ni = 0; ni < 4; ++ni)
                acc[mi + 4][ni] = __builtin_amdgcn_mfma_i32_16x16x64_i8(af[mi], bf[ni], acc[mi + 4][ni], 0, 0, 0);
        __builtin_amdgcn_s_setprio(0);
        __builtin_amdgcn_s_barrier();

        // ---- P3: ks1, mh0 | stage A-ks1(t+1) ----
#pragma unroll
        for (int mi = 0; mi < 4; ++mi)
            af[mi] = *(const i32x4*)(lds + bofs + aoff + 16384 + mi * 1024);
#pragma unroll
        for (int ni = 0; ni < 4; ++ni)
            bf[ni] = *(const i32x4*)(lds + bofs + boff + 16384 + ni * 1024);
        G2L(Ab + arow0 + kc + 64 + gslot, lds + nbofs + 16384 + sdst);
        G2L(Ab + arow1 + kc + 64 + gslot, lds + nbofs + 16384 + 8192 + sdst);
        __builtin_amdgcn_s_barrier();
        __builtin_amdgcn_s_setprio(1);
#pragma unroll
        for (int mi = 0; mi < 4; ++mi)
#pragma unroll
            for (int ni = 0; ni < 4; ++ni)
                acc[mi][ni] = __builtin_amdgcn_mfma_i32_16x16x64_i8(af[mi], bf[ni], acc[mi][ni], 0, 0, 0);
        __builtin_amdgcn_s_setprio(0);
        __builtin_amdgcn_s_barrier();

        // ---- P4: ks1, mh1 | stage B-ks1(t+1) | vmcnt(4) ----
#pragma unroll
        for (int mi = 0; mi < 4; ++mi)
            af[mi] = *(const i32x4*)(lds + bofs + aoff + 16384 + 4096 + mi * 1024);
        G2L(Bb + arow0 + kc + 64 + gslot, lds + nbofs + 65536 + 16384 + sdst);
        G2L(Bb + arow1 + kc + 64 + gslot, lds + nbofs + 65536 + 16384 + 8192 + sdst);
        asm volatile("s_waitcnt vmcnt(4)" ::: "memory");   // ks0(t+1) slabs landed
        __builtin_amdgcn_s_barrier();
        __builtin_amdgcn_s_setprio(1);
#pragma unroll
        for (int mi = 0; mi < 4; ++mi)
#pragma unroll
            for (int ni = 0; ni < 4; ++ni)
                acc[mi + 4][ni] = __builtin_amdgcn_mfma_i32_16x16x64_i8(af[mi], bf[ni], acc[mi + 4][ni], 0, 0, 0);
        __builtin_amdgcn_s_setprio(0);
        __builtin_amdgcn_s_barrier();
    }

    // epilogue: out = acc * x_scale[m] * w_scale[n] + bias[n]  (bit-identical math)
#pragma unroll
    for (int ni = 0; ni < 4; ++ni) {
        int gn = bn * 256 + wc * 64 + ni * 16 + r16;
        float wv = wsc[gn];
        float bv = bias[gn];
#pragma unroll
        for (int mi = 0; mi < 8; ++mi) {
#pragma unroll
            for (int i = 0; i < 4; ++i) {
                int gm = bm * 256 + wr * 128 + mi * 16 + quad * 4 + i;
                out[(size_t)gm * N + gn] = (float)acc[mi][ni][i] * xs[gm] * wv + bv;
            }
        }
    }
}

// ---------------------------------------------------------------------------
extern "C" void kernel_launch(void* const* d_in, const int* in_sizes, int n_in,
                              void* d_out, int out_size, void* d_ws, size_t ws_size,
                              hipStream_t stream)
{
    const float* x    = (const float*)d_in[0];
    const float* w    = (const float*)d_in[1];
    const float* bias = (const float*)d_in[2];
    float* out = (float*)d_out;

    const int N = in_sizes[2];
    const int K = in_sizes[1] / N;
    const int M = in_sizes[0] / K;

    // workspace layout
    float* xmax   = (float*)d_ws;                 // K
    float* wmax   = xmax + K;                     // K
    float* smooth = wmax + K;                     // K
    float* xscale = smooth + K;                   // M
    float* wscale = xscale + M;                   // N
    signed char* xq = (signed char*)(wscale + N); // M*K
    signed char* wq = xq + (size_t)M * K;         // N*K

    hipMemsetAsync(xmax, 0, (size_t)2 * K * sizeof(float), stream);

    colmax_kernel<<<dim3(K / 1024, M / 64), 256, 0, stream>>>(x, K, xmax);
    colmax_kernel<<<dim3(K / 1024, N / 64), 256, 0, stream>>>(w, K, wmax);
    smooth_kernel<<<dim3((K + 255) / 256), 256, 0, stream>>>(xmax, wmax, smooth, K);
    quant_kernel<false><<<dim3(M), 256, 0, stream>>>(x, smooth, xq, xscale, K);
    quant_kernel<true ><<<dim3(N), 256, 0, stream>>>(w, smooth, wq, wscale, K);
    gemm_i8_256<<<dim3(N / 256, M / 256), 512, 0, stream>>>(
        xq, wq, xscale, wscale, bias, out, M, N, K);
}

// Round 4
// 1392.707 us; speedup vs baseline: 1.2557x; 1.0184x over previous
//
#include <hip/hip_runtime.h>
#include <hip/hip_bf16.h>

typedef __attribute__((ext_vector_type(4))) int i32x4;

// ---------------------------------------------------------------------------
// exact pow2 ceil: smallest power of two >= s  (s > 0, normal)
// ---------------------------------------------------------------------------
__device__ inline float pow2_ceil(float s) {
    unsigned u = __float_as_uint(s);
    if ((u & 0x007fffffu) == 0) return s;              // exact power of two
    return __uint_as_float(((u >> 23) + 1) << 23);     // bump exponent
}

// ---------------------------------------------------------------------------
// fused column absmax over x AND w in one dispatch.
// 32 rows/block, explicit 4-row load batches -> guaranteed 4-deep MLP.
// grid: (K/1024, M/32 + N/32), 256 thr; vals >= 0 so atomicMax-as-uint valid.
// ---------------------------------------------------------------------------
__global__ __launch_bounds__(256) void colmax2_kernel(
    const float* __restrict__ x, const float* __restrict__ w,
    int K, int xblocks, float* __restrict__ xmax, float* __restrict__ wmax)
{
    const int by = blockIdx.y;
    const float* src;
    float* out;
    if (by < xblocks) { src = x + (size_t)by * 32 * K;            out = xmax; }
    else              { src = w + (size_t)(by - xblocks) * 32 * K; out = wmax; }

    int col = (blockIdx.x * 256 + threadIdx.x) * 4;
    const float* p = src + col;
    float m0 = 0.f, m1 = 0.f, m2 = 0.f, m3 = 0.f;
#pragma unroll
    for (int r = 0; r < 32; r += 4) {
        float4 a = *(const float4*)(p);
        float4 b = *(const float4*)(p + K);
        float4 c = *(const float4*)(p + 2 * (size_t)K);
        float4 d = *(const float4*)(p + 3 * (size_t)K);
        p += 4 * (size_t)K;
        m0 = fmaxf(fmaxf(m0, fabsf(a.x)), fmaxf(fmaxf(fabsf(b.x), fabsf(c.x)), fabsf(d.x)));
        m1 = fmaxf(fmaxf(m1, fabsf(a.y)), fmaxf(fmaxf(fabsf(b.y), fabsf(c.y)), fabsf(d.y)));
        m2 = fmaxf(fmaxf(m2, fabsf(a.z)), fmaxf(fmaxf(fabsf(b.z), fabsf(c.z)), fabsf(d.z)));
        m3 = fmaxf(fmaxf(m3, fabsf(a.w)), fmaxf(fmaxf(fabsf(b.w), fabsf(c.w)), fabsf(d.w)));
    }
    atomicMax((unsigned int*)(out + col + 0), __float_as_uint(m0));
    atomicMax((unsigned int*)(out + col + 1), __float_as_uint(m1));
    atomicMax((unsigned int*)(out + col + 2), __float_as_uint(m2));
    atomicMax((unsigned int*)(out + col + 3), __float_as_uint(m3));
}

__global__ __launch_bounds__(256) void smooth_kernel(
    const float* __restrict__ xmax, const float* __restrict__ wmax,
    float* __restrict__ smooth, int K)
{
    int i = blockIdx.x * 256 + threadIdx.x;
    if (i < K) smooth[i] = sqrtf(xmax[i] * wmax[i]);
}

// ---------------------------------------------------------------------------
// per-row quant (unchanged — math must stay bit-identical to reference)
// ---------------------------------------------------------------------------
template <bool MUL>
__global__ __launch_bounds__(256) void quant_kernel(
    const float* __restrict__ src, const float* __restrict__ smooth,
    signed char* __restrict__ q, float* __restrict__ scale_out, int K)
{
    __shared__ float red[4];
    const int row = blockIdx.x;
    const int tid = threadIdx.x;
    const float* sr = src + (size_t)row * K;

    float v[16];
    float amax = 0.f;
#pragma unroll
    for (int c = 0; c < 4; ++c) {
        int idx = (c << 10) + (tid << 2);
        float4 xv = *(const float4*)(sr + idx);
        float4 sv = *(const float4*)(smooth + idx);
        float a, b, cc, d;
        if (MUL) { a = xv.x * sv.x; b = xv.y * sv.y; cc = xv.z * sv.z; d = xv.w * sv.w; }
        else     { a = xv.x / sv.x; b = xv.y / sv.y; cc = xv.z / sv.z; d = xv.w / sv.w; }
        v[c*4+0] = a; v[c*4+1] = b; v[c*4+2] = cc; v[c*4+3] = d;
        amax = fmaxf(amax, fmaxf(fmaxf(fabsf(a), fabsf(b)), fmaxf(fabsf(cc), fabsf(d))));
    }
#pragma unroll
    for (int off = 32; off > 0; off >>= 1)
        amax = fmaxf(amax, __shfl_down(amax, off, 64));
    if ((tid & 63) == 0) red[tid >> 6] = amax;
    __syncthreads();
    float m = fmaxf(fmaxf(red[0], red[1]), fmaxf(red[2], red[3]));

    float s = fmaxf(m / 127.0f, 1e-30f);
    float scale = pow2_ceil(s);
    if (tid == 0) scale_out[row] = scale;
    float inv = 1.0f / scale;

#pragma unroll
    for (int c = 0; c < 4; ++c) {
        char4 o;
        o.x = (signed char)(int)fminf(fmaxf(rintf(v[c*4+0] * inv), -127.f), 127.f);
        o.y = (signed char)(int)fminf(fmaxf(rintf(v[c*4+1] * inv), -127.f), 127.f);
        o.z = (signed char)(int)fminf(fmaxf(rintf(v[c*4+2] * inv), -127.f), 127.f);
        o.w = (signed char)(int)fminf(fmaxf(rintf(v[c*4+3] * inv), -127.f), 127.f);
        *(char4*)(q + (size_t)row * K + (c << 10) + (tid << 2)) = o;
    }
}

// ---------------------------------------------------------------------------
// i8 GEMM, 256x256 8-phase template (T1+T2+T3+T4+T5 per learn_hip m201):
//   BM=BN=256, BK=128 i8; 8 waves (2M x 4N), 512 thr; per-wave 128x64
//   LDS 128 KiB: 2 dbuf x 2 K-slabs(64B) x (A 16KB + B 16KB)
//   per K-tile: 4 phases x 16 mfma_i32_16x16x64_i8; counted vmcnt(4) 2x/tile
// Bank swizzle: phys 16B-slot = logical ^ ((row>>1)&3).
//   Bank-quad of a read = (row&1)*4 + (slot ^ (row>>1)&3) -> over 16 rows a
//   16-lane group hits all 8 bank-quads exactly twice = wave64 b128 minimum.
//   (Round-2 mask row&3 collapsed to 4 quads / 4 lanes each -> 5e7 conflicts.)
// vmcnt ledger (per wave): prologue 8 -> vmcnt(4); P1+2, P2+2 -> vmcnt(4)
//   retires ks1(t); P3+2, P4+2 -> vmcnt(4) retires ks0(t+1). Never 0 in loop.
// ---------------------------------------------------------------------------
#define G2L(g, l) __builtin_amdgcn_global_load_lds( \
    (const __attribute__((address_space(1))) unsigned char*)(g), \
    (__attribute__((address_space(3))) unsigned char*)(l), 16, 0, 0)

__global__ __launch_bounds__(512, 2) void gemm_i8_256(
    const signed char* __restrict__ Aq, const signed char* __restrict__ Bq,
    const float* __restrict__ xs, const float* __restrict__ wsc,
    const float* __restrict__ bias, float* __restrict__ out,
    int M, int N, int K)
{
    __shared__ signed char lds[131072];   // A: [0,64K) B: [64K,128K)

    const int tid = threadIdx.x;

    // T1: bijective XCD-aware block swizzle (m204 formula)
    const int nbx = gridDim.x;                       // N/256
    int lid = blockIdx.y * nbx + blockIdx.x;
    const int nwg = nbx * gridDim.y;
    const int q8 = nwg >> 3, r8 = nwg & 7;
    const int xcd = lid & 7, idx = lid >> 3;
    lid = (xcd < r8 ? xcd * (q8 + 1) : r8 * (q8 + 1) + (xcd - r8) * q8) + idx;
    const int bm = lid / nbx, bn = lid % nbx;

    const int lane = tid & 63;
    const int wave = tid >> 6;
    const int r16 = lane & 15, quad = lane >> 4;
    const int wr = wave >> 2;        // 0..1  (M half: 128 rows)
    const int wc = wave & 3;         // 0..3  (N quarter: 64 cols)

    const signed char* Ab = Aq + (size_t)(bm * 256) * K;
    const signed char* Bb = Bq + (size_t)(bn * 256) * K;

    // staging geometry: thread covers slab row tid>>2, 16B slot tid&3
    const int srow  = tid >> 2;
    const int sslot = tid & 3;
    const int gslot = ((sslot ^ ((srow >> 1) & 3)) << 4);  // swizzled src slot
    const size_t arow0 = (size_t)srow * K;
    const size_t arow1 = (size_t)(srow + 128) * K;         // ((srow+128)>>1)&3 == (srow>>1)&3
    const int sdst = tid << 4;                             // linear LDS dest (+ p*8192)

    // reader: phys slot = quad ^ ((row>>1)&3); row = wr*128+mi*16+r16 -> (r16>>1)&3
    const int sw   = (quad ^ ((r16 >> 1) & 3)) << 4;
    const int aoff = ((wr * 128 + r16) << 6) + sw;           // + mi*1024 + ks*16384 + buf
    const int boff = 65536 + ((wc * 64 + r16) << 6) + sw;    // + ni*1024 + ks*16384 + buf

    i32x4 acc[8][4] = {};
    const int NT = K >> 7;   // K-tiles of 128

    // ---- prologue: stage all 4 slabs of tile 0 into buf 0 ----
    G2L(Ab + arow0 + gslot,              lds + sdst);                      // A-ks0
    G2L(Ab + arow1 + gslot,              lds + 8192 + sdst);
    G2L(Bb + arow0 + gslot,              lds + 65536 + sdst);              // B-ks0
    G2L(Bb + arow1 + gslot,              lds + 65536 + 8192 + sdst);
    G2L(Ab + arow0 + 64 + gslot,         lds + 16384 + sdst);              // A-ks1
    G2L(Ab + arow1 + 64 + gslot,         lds + 16384 + 8192 + sdst);
    G2L(Bb + arow0 + 64 + gslot,         lds + 65536 + 16384 + sdst);      // B-ks1
    G2L(Bb + arow1 + 64 + gslot,         lds + 65536 + 16384 + 8192 + sdst);
    asm volatile("s_waitcnt vmcnt(4)" ::: "memory");   // ks0 slabs landed
    __builtin_amdgcn_s_barrier();

    for (int t = 0; t < NT; ++t) {
        const int bofs  = (t & 1) << 15;
        const int nbofs = bofs ^ 32768;
        const size_t kc = (size_t)((t + 1 < NT) ? (t + 1) : t) << 7;  // clamped prefetch
        i32x4 af[4], bf[4];

        // ---- P1: ks0, mh0 | stage A-ks0(t+1) ----
#pragma unroll
        for (int mi = 0; mi < 4; ++mi)
            af[mi] = *(const i32x4*)(lds + bofs + aoff + mi * 1024);
#pragma unroll
        for (int ni = 0; ni < 4; ++ni)
            bf[ni] = *(const i32x4*)(lds + bofs + boff + ni * 1024);
        G2L(Ab + arow0 + kc + gslot, lds + nbofs + sdst);
        G2L(Ab + arow1 + kc + gslot, lds + nbofs + 8192 + sdst);
        __builtin_amdgcn_s_barrier();
        __builtin_amdgcn_s_setprio(1);
#pragma unroll
        for (int mi = 0; mi < 4; ++mi)
#pragma unroll
            for (int ni = 0; ni < 4; ++ni)
                acc[mi][ni] = __builtin_amdgcn_mfma_i32_16x16x64_i8(af[mi], bf[ni], acc[mi][ni], 0, 0, 0);
        __builtin_amdgcn_s_setprio(0);
        __builtin_amdgcn_s_barrier();

        // ---- P2: ks0, mh1 | stage B-ks0(t+1) | vmcnt(4) ----
#pragma unroll
        for (int mi = 0; mi < 4; ++mi)
            af[mi] = *(const i32x4*)(lds + bofs + aoff + 4096 + mi * 1024);
        G2L(Bb + arow0 + kc + gslot, lds + nbofs + 65536 + sdst);
        G2L(Bb + arow1 + kc + gslot, lds + nbofs + 65536 + 8192 + sdst);
        asm volatile("s_waitcnt vmcnt(4)" ::: "memory");   // ks1(t) slabs landed
        __builtin_amdgcn_s_barrier();
        __builtin_amdgcn_s_setprio(1);
#pragma unroll
        for (int mi = 0; mi < 4; ++mi)
#pragma unroll
            for (int ni = 0; ni < 4; ++ni)
                acc[mi + 4][ni] = __builtin_amdgcn_mfma_i32_16x16x64_i8(af[mi], bf[ni], acc[mi + 4][ni], 0, 0, 0);
        __builtin_amdgcn_s_setprio(0);
        __builtin_amdgcn_s_barrier();

        // ---- P3: ks1, mh0 | stage A-ks1(t+1) ----
#pragma unroll
        for (int mi = 0; mi < 4; ++mi)
            af[mi] = *(const i32x4*)(lds + bofs + aoff + 16384 + mi * 1024);
#pragma unroll
        for (int ni = 0; ni < 4; ++ni)
            bf[ni] = *(const i32x4*)(lds + bofs + boff + 16384 + ni * 1024);
        G2L(Ab + arow0 + kc + 64 + gslot, lds + nbofs + 16384 + sdst);
        G2L(Ab + arow1 + kc + 64 + gslot, lds + nbofs + 16384 + 8192 + sdst);
        __builtin_amdgcn_s_barrier();
        __builtin_amdgcn_s_setprio(1);
#pragma unroll
        for (int mi = 0; mi < 4; ++mi)
#pragma unroll
            for (int ni = 0; ni < 4; ++ni)
                acc[mi][ni] = __builtin_amdgcn_mfma_i32_16x16x64_i8(af[mi], bf[ni], acc[mi][ni], 0, 0, 0);
        __builtin_amdgcn_s_setprio(0);
        __builtin_amdgcn_s_barrier();

        // ---- P4: ks1, mh1 | stage B-ks1(t+1) | vmcnt(4) ----
#pragma unroll
        for (int mi = 0; mi < 4; ++mi)
            af[mi] = *(const i32x4*)(lds + bofs + aoff + 16384 + 4096 + mi * 1024);
        G2L(Bb + arow0 + kc + 64 + gslot, lds + nbofs + 65536 + 16384 + sdst);
        G2L(Bb + arow1 + kc + 64 + gslot, lds + nbofs + 65536 + 16384 + 8192 + sdst);
        asm volatile("s_waitcnt vmcnt(4)" ::: "memory");   // ks0(t+1) slabs landed
        __builtin_amdgcn_s_barrier();
        __builtin_amdgcn_s_setprio(1);
#pragma unroll
        for (int mi = 0; mi < 4; ++mi)
#pragma unroll
            for (int ni = 0; ni < 4; ++ni)
                acc[mi + 4][ni] = __builtin_amdgcn_mfma_i32_16x16x64_i8(af[mi], bf[ni], acc[mi + 4][ni], 0, 0, 0);
        __builtin_amdgcn_s_setprio(0);
        __builtin_amdgcn_s_barrier();
    }

    // epilogue: out = acc * x_scale[m] * w_scale[n] + bias[n]  (bit-identical math)
#pragma unroll
    for (int ni = 0; ni < 4; ++ni) {
        int gn = bn * 256 + wc * 64 + ni * 16 + r16;
        float wv = wsc[gn];
        float bv = bias[gn];
#pragma unroll
        for (int mi = 0; mi < 8; ++mi) {
#pragma unroll
            for (int i = 0; i < 4; ++i) {
                int gm = bm * 256 + wr * 128 + mi * 16 + quad * 4 + i;
                out[(size_t)gm * N + gn] = (float)acc[mi][ni][i] * xs[gm] * wv + bv;
            }
        }
    }
}

// ---------------------------------------------------------------------------
extern "C" void kernel_launch(void* const* d_in, const int* in_sizes, int n_in,
                              void* d_out, int out_size, void* d_ws, size_t ws_size,
                              hipStream_t stream)
{
    const float* x    = (const float*)d_in[0];
    const float* w    = (const float*)d_in[1];
    const float* bias = (const float*)d_in[2];
    float* out = (float*)d_out;

    const int N = in_sizes[2];
    const int K = in_sizes[1] / N;
    const int M = in_sizes[0] / K;

    // workspace layout
    float* xmax   = (float*)d_ws;                 // K
    float* wmax   = xmax + K;                     // K
    float* smooth = wmax + K;                     // K
    float* xscale = smooth + K;                   // M
    float* wscale = xscale + M;                   // N
    signed char* xq = (signed char*)(wscale + N); // M*K
    signed char* wq = xq + (size_t)M * K;         // N*K

    hipMemsetAsync(xmax, 0, (size_t)2 * K * sizeof(float), stream);

    const int xblocks = M / 32;
    colmax2_kernel<<<dim3(K / 1024, xblocks + N / 32), 256, 0, stream>>>(
        x, w, K, xblocks, xmax, wmax);
    smooth_kernel<<<dim3((K + 255) / 256), 256, 0, stream>>>(xmax, wmax, smooth, K);
    quant_kernel<false><<<dim3(M), 256, 0, stream>>>(x, smooth, xq, xscale, K);
    quant_kernel<true ><<<dim3(N), 256, 0, stream>>>(w, smooth, wq, wscale, K);
    gemm_i8_256<<<dim3(N / 256, M / 256), 512, 0, stream>>>(
        xq, wq, xscale, wscale, bias, out, M, N, K);
}